// Round 2
// baseline (473.024 us; speedup 1.0000x reference)
//
#include <hip/hip_runtime.h>

#define B_ 2048
#define N_ 200
#define D_ 128
#define NE1 4   // NE+1
#define NN1 3   // NN+1

// ---------------------------------------------------------------------------
// Mask storage detection (bool-bytes vs int32). Flag -> ws[0].
// ---------------------------------------------------------------------------
__global__ void detect_mask_kernel(const unsigned int* __restrict__ mw,
                                   int nwords, unsigned int* __restrict__ flag) {
  __shared__ int sbad;
  if (threadIdx.x == 0) sbad = 0;
  __syncthreads();
  int bad = 0;
  for (int i = blockIdx.x * blockDim.x + threadIdx.x; i < nwords;
       i += gridDim.x * blockDim.x)
    if (mw[i] > 1u) bad = 1;
  if (bad) sbad = 1;
  __syncthreads();
  if (threadIdx.x == 0 && sbad) atomicOr(flag, 1u);
}

// ---------------------------------------------------------------------------
// Prep: qM[b, e*4+h, d] = pri[h,u_b,e]/sqrt(32) * sum_i (Wq[e]q_b)[h*32+i] * Wk[e][h*32+i][d]
// One block per (e, 16-b tile). Weights amortized over 16 b.
// ---------------------------------------------------------------------------
__global__ __launch_bounds__(256) void prep_kernel(
    const float* __restrict__ q, const float* __restrict__ Wq,
    const float* __restrict__ Wk, const float* __restrict__ rel_pri,
    const int* __restrict__ utype, float* __restrict__ qM) {
  const int e = blockIdx.x & 3;
  const int b0 = (blockIdx.x >> 2) * 16;
  const int tid = threadIdx.x;

  __shared__ float q_s[16][132];
  __shared__ float Qe_s[16][132];
  __shared__ float pri_s[16][4];
  __shared__ int u_s[16];

  for (int idx = tid; idx < 16 * 32; idx += 256) {
    int r = idx >> 5, c = idx & 31;
    ((float4*)&q_s[r][0])[c] = ((const float4*)(q + (size_t)(b0 + r) * 128))[c];
  }
  if (tid < 16) u_s[tid] = utype[b0 + tid];
  __syncthreads();

  if (tid < 64) {
    int bl = tid >> 2, h = tid & 3;
    pri_s[bl][h] =
        rel_pri[(h * NN1 + u_s[bl]) * NE1 + e] * 0.17677669529663687f;
  }

  // Step A: Qe_s[b][j] = Wq[e][j][:] . q[b]
  {
    const int j = tid & 127, half = tid >> 7;
    float acc[8] = {0, 0, 0, 0, 0, 0, 0, 0};
    const float4* wq = (const float4*)(Wq + ((size_t)e * 128 + j) * 128);
    for (int c = 0; c < 32; ++c) {
      float4 w = wq[c];
#pragma unroll
      for (int bg = 0; bg < 8; ++bg) {
        float4 qq = ((const float4*)&q_s[half * 8 + bg][0])[c];
        acc[bg] += w.x * qq.x + w.y * qq.y + w.z * qq.z + w.w * qq.w;
      }
    }
#pragma unroll
    for (int bg = 0; bg < 8; ++bg) Qe_s[half * 8 + bg][j] = acc[bg];
  }
  __syncthreads();

  // Step B: qM[b, e*4+h, d] = sum_i Qe_s[b][h*32+i] * Wk[e][h*32+i][d]
  {
    const int d = tid & 127, half = tid >> 7;
    for (int h = 0; h < 4; ++h) {
      float acc[8] = {0, 0, 0, 0, 0, 0, 0, 0};
#pragma unroll
      for (int i4 = 0; i4 < 8; ++i4) {
        const float* wkp = Wk + ((size_t)e * 128 + h * 32 + i4 * 4) * 128 + d;
        float w0 = wkp[0], w1 = wkp[128], w2 = wkp[256], w3 = wkp[384];
#pragma unroll
        for (int bg = 0; bg < 8; ++bg) {
          float4 qe = ((const float4*)&Qe_s[half * 8 + bg][0])[h * 8 + i4];
          acc[bg] = fmaf(qe.x, w0, acc[bg]);
          acc[bg] = fmaf(qe.y, w1, acc[bg]);
          acc[bg] = fmaf(qe.z, w2, acc[bg]);
          acc[bg] = fmaf(qe.w, w3, acc[bg]);
        }
      }
#pragma unroll
      for (int bg = 0; bg < 8; ++bg) {
        int bl = half * 8 + bg;
        qM[((size_t)(b0 + bl) * 16 + e * 4 + h) * 128 + d] =
            acc[bg] * pri_s[bl][h];
      }
    }
  }
}

// ---------------------------------------------------------------------------
// Stream: per-b logits + softmax + PV + Wv-contract + FC + LN. ~13.5 KB LDS.
// ---------------------------------------------------------------------------
__global__ __launch_bounds__(256) void stream_kernel(
    const float* __restrict__ qM, const float* __restrict__ k,
    const float* __restrict__ v, const float* __restrict__ Wv,
    const float* __restrict__ W_fc, const float* __restrict__ b_fc,
    const float* __restrict__ ln_gamma, const float* __restrict__ ln_beta,
    const float* __restrict__ q, const int* __restrict__ etype,
    const int* __restrict__ utype, const void* __restrict__ maskp,
    const unsigned int* __restrict__ flag, float* __restrict__ y_out,
    float* __restrict__ attn_out) {
  const int b = blockIdx.x, tid = threadIdx.x;

  __shared__ float qm_s[16][132];  // qM, later reused for s[h][e][:]
  __shared__ float p_s[4][200];    // logits -> probs; later FC partials
  __shared__ int et_s[200];
  __shared__ float part_s[256];
  __shared__ float red_s[8];
  __shared__ int u_s;

  if (tid == 0) u_s = utype[b];
  {
    const float4* src = (const float4*)(qM + (size_t)b * 2048);
    for (int idx = tid; idx < 512; idx += 256) {
      int r = idx >> 5, c = idx & 31;
      ((float4*)&qm_s[r][0])[c] = src[idx];
    }
  }
  for (int i = tid; i < N_; i += 256) et_s[i] = etype[(size_t)b * N_ + i];
  __syncthreads();

  // ---- logits: thread n computes 4 head dots ----
  if (tid < N_) {
    const int n = tid;
    const float4* kr = (const float4*)(k + ((size_t)b * N_ + n) * 128);
    const int eh0 = et_s[n] * 4;
    float a0 = 0.f, a1 = 0.f, a2 = 0.f, a3 = 0.f;
    for (int co = 0; co < 4; ++co) {
      float4 kb[8];
#pragma unroll
      for (int cc = 0; cc < 8; ++cc) kb[cc] = kr[co * 8 + cc];
#pragma unroll
      for (int cc = 0; cc < 8; ++cc) {
        int c = co * 8 + cc;
        float4 m0 = ((const float4*)&qm_s[eh0 + 0][0])[c];
        float4 m1 = ((const float4*)&qm_s[eh0 + 1][0])[c];
        float4 m2 = ((const float4*)&qm_s[eh0 + 2][0])[c];
        float4 m3 = ((const float4*)&qm_s[eh0 + 3][0])[c];
        a0 += kb[cc].x * m0.x + kb[cc].y * m0.y + kb[cc].z * m0.z + kb[cc].w * m0.w;
        a1 += kb[cc].x * m1.x + kb[cc].y * m1.y + kb[cc].z * m1.z + kb[cc].w * m1.w;
        a2 += kb[cc].x * m2.x + kb[cc].y * m2.y + kb[cc].z * m2.z + kb[cc].w * m2.w;
        a3 += kb[cc].x * m3.x + kb[cc].y * m3.y + kb[cc].z * m3.z + kb[cc].w * m3.w;
      }
    }
    int m;
    if (flag[0])
      m = ((const unsigned char*)maskp)[(size_t)b * N_ + n];
    else
      m = ((const int*)maskp)[(size_t)b * N_ + n];
    if (m) { a0 = a1 = a2 = a3 = -1e10f; }
    p_s[0][n] = a0;
    p_s[1][n] = a1;
    p_s[2][n] = a2;
    p_s[3][n] = a3;
  }
  __syncthreads();

  // ---- softmax (wave per head) + attn write ----
  {
    const int w = tid >> 6, l = tid & 63;
    float mx = -1e30f;
    for (int n = l; n < N_; n += 64) mx = fmaxf(mx, p_s[w][n]);
#pragma unroll
    for (int o = 32; o; o >>= 1) mx = fmaxf(mx, __shfl_xor(mx, o));
    float sum = 0.f;
    for (int n = l; n < N_; n += 64) {
      float e = __expf(p_s[w][n] - mx);
      p_s[w][n] = e;
      sum += e;
    }
#pragma unroll
    for (int o = 32; o; o >>= 1) sum += __shfl_xor(sum, o);
    float inv = 1.f / sum;
    for (int n = l; n < N_; n += 64) {
      float pp = p_s[w][n] * inv;
      p_s[w][n] = pp;
      attn_out[((size_t)w * B_ + b) * N_ + n] = pp;
    }
  }
  __syncthreads();

  // ---- PV: s[h][e][d] accumulate; h per wave, d-pair per lane ----
  {
    const int h = tid >> 6, d0 = tid & 63;
    float a0[4] = {0.f, 0.f, 0.f, 0.f}, a1[4] = {0.f, 0.f, 0.f, 0.f};
    const float* vb = v + (size_t)b * N_ * 128;
    for (int n = 0; n < N_; ++n) {
      float pv = p_s[h][n];
      int en = et_s[n];
      float v0 = vb[n * 128 + d0], v1 = vb[n * 128 + 64 + d0];
#pragma unroll
      for (int e = 0; e < 4; ++e) {
        float sel = (en == e) ? pv : 0.f;
        a0[e] = fmaf(sel, v0, a0[e]);
        a1[e] = fmaf(sel, v1, a1[e]);
      }
    }
#pragma unroll
    for (int e = 0; e < 4; ++e) {
      qm_s[e * 4 + h][d0] = a0[e];
      qm_s[e * 4 + h][64 + d0] = a1[e];
    }
  }
  __syncthreads();

  // ---- Wv contract: out[row] split across e-halves ----
  {
    const int row = tid & 127, halfE = tid >> 7;
    const int hh = row >> 5;
    float acc = 0.f;
#pragma unroll
    for (int ee = 0; ee < 2; ++ee) {
      int e = halfE * 2 + ee;
      const float4* wr = (const float4*)(Wv + ((size_t)e * 128 + row) * 128);
      const float4* ss = (const float4*)&qm_s[e * 4 + hh][0];
      for (int c = 0; c < 32; ++c) {
        float4 w = wr[c], sv = ss[c];
        acc += w.x * sv.x + w.y * sv.y + w.z * sv.z + w.w * sv.w;
      }
    }
    part_s[tid] = acc;
  }
  __syncthreads();

  // ---- FC: split r-range across thread halves; partials into p_s ----
  {
    const int j = tid & 127, halfR = tid >> 7;
    const float* wf = W_fc + ((size_t)u_s * 128 + halfR * 64) * 128 + j;
    float acc = 0.f;
#pragma unroll 4
    for (int r = 0; r < 64; ++r) {
      float o = part_s[halfR * 64 + r] + part_s[128 + halfR * 64 + r];
      acc = fmaf(o, wf[r * 128], acc);
    }
    ((float*)p_s)[tid] = acc;
  }
  __syncthreads();

  // ---- residual + LayerNorm ----
  float x = 0.f;
  if (tid < 128) {
    x = ((float*)p_s)[tid] + ((float*)p_s)[128 + tid] + b_fc[u_s * 128 + tid] +
        q[(size_t)b * 128 + tid];
  }
  float s1 = (tid < 128) ? x : 0.f, s2 = (tid < 128) ? x * x : 0.f;
#pragma unroll
  for (int o = 32; o; o >>= 1) {
    s1 += __shfl_xor(s1, o);
    s2 += __shfl_xor(s2, o);
  }
  if (tid < 128 && (tid & 63) == 0) {
    red_s[tid >> 6] = s1;
    red_s[4 + (tid >> 6)] = s2;
  }
  __syncthreads();
  if (tid < 128) {
    float t1 = red_s[0] + red_s[1], t2 = red_s[4] + red_s[5];
    float mu = t1 * (1.f / 128.f);
    float var = t2 * (1.f / 128.f) - mu * mu;
    float yv =
        (x - mu) * rsqrtf(var + 1e-5f) * ln_gamma[tid] + ln_beta[tid];
    y_out[(size_t)b * 128 + tid] = yv;
  }
}

extern "C" void kernel_launch(void* const* d_in, const int* in_sizes, int n_in,
                              void* d_out, int out_size, void* d_ws,
                              size_t ws_size, hipStream_t stream) {
  const float* q = (const float*)d_in[0];
  const float* k = (const float*)d_in[1];
  const float* v = (const float*)d_in[2];
  const float* Wq = (const float*)d_in[3];
  const float* Wk = (const float*)d_in[4];
  const float* Wv = (const float*)d_in[5];
  const float* rp = (const float*)d_in[6];
  const float* Wf = (const float*)d_in[7];
  const float* bf = (const float*)d_in[8];
  const float* g = (const float*)d_in[9];
  const float* be = (const float*)d_in[10];
  const int* et = (const int*)d_in[11];
  const int* ut = (const int*)d_in[12];
  const void* mask = d_in[13];

  float* y = (float*)d_out;
  float* attn = y + (size_t)B_ * D_;
  unsigned int* flag = (unsigned int*)d_ws;
  float* qM = (float*)((char*)d_ws + 256);  // 2048*16*128 floats = 16.8 MB

  hipMemsetAsync(d_ws, 0, 4, stream);
  detect_mask_kernel<<<64, 256, 0, stream>>>((const unsigned int*)mask,
                                             B_ * N_ / 4, flag);
  prep_kernel<<<512, 256, 0, stream>>>(q, Wq, Wk, rp, ut, qM);
  stream_kernel<<<B_, 256, 0, stream>>>(qM, k, v, Wv, Wf, bf, g, be, q, et, ut,
                                        mask, flag, y, attn);
}

// Round 3
// 266.440 us; speedup vs baseline: 1.7754x; 1.7754x over previous
//
#include <hip/hip_runtime.h>

#define B_ 2048
#define N_ 200
#define D_ 128
#define NE1 4   // NE+1
#define NN1 3   // NN+1

// ---------------------------------------------------------------------------
// Mask storage detection (bool-bytes vs int32). Flag -> ws[0].
// ---------------------------------------------------------------------------
__global__ void detect_mask_kernel(const unsigned int* __restrict__ mw,
                                   int nwords, unsigned int* __restrict__ flag) {
  __shared__ int sbad;
  if (threadIdx.x == 0) sbad = 0;
  __syncthreads();
  int bad = 0;
  for (int i = blockIdx.x * blockDim.x + threadIdx.x; i < nwords;
       i += gridDim.x * blockDim.x)
    if (mw[i] > 1u) bad = 1;
  if (bad) sbad = 1;
  __syncthreads();
  if (threadIdx.x == 0 && sbad) atomicOr(flag, 1u);
}

// ---------------------------------------------------------------------------
// Fused kernel: one block per batch element b. ~16 KB LDS, VGPR<=64 target.
// ---------------------------------------------------------------------------
__global__ __launch_bounds__(256, 8) void fused_mha_kernel(
    const float* __restrict__ q, const float* __restrict__ k,
    const float* __restrict__ v, const float* __restrict__ Wq,
    const float* __restrict__ Wk, const float* __restrict__ Wv,
    const float* __restrict__ rel_pri, const float* __restrict__ W_fc,
    const float* __restrict__ b_fc, const float* __restrict__ ln_gamma,
    const float* __restrict__ ln_beta, const int* __restrict__ etype,
    const int* __restrict__ utype, const void* __restrict__ maskp,
    const unsigned int* __restrict__ flag, float* __restrict__ y_out,
    float* __restrict__ attn_out) {
  const int b = blockIdx.x;
  const int tid = threadIdx.x;

  __shared__ float q_s[128];
  __shared__ float Qe_s[4][132];
  __shared__ float ehbuf[16][132];  // qM (scaled); later s[h][e][:]
  __shared__ float p_s[4][200];     // logits -> probs; later FC partials
  __shared__ int et_s[200];
  __shared__ float pri_s[16];  // [e*4+h], includes 1/sqrt(dk)
  __shared__ float part_s[256];
  __shared__ float red_s[8];
  __shared__ int u_s;

  // ---------------- Phase 0: per-b metadata ----------------
  if (tid == 0) u_s = utype[b];
  if (tid < 128) q_s[tid] = q[(size_t)b * D_ + tid];
  for (int i = tid; i < N_; i += 256) et_s[i] = etype[(size_t)b * N_ + i];
  __syncthreads();
  if (tid < 16) {
    int e = tid >> 2, h = tid & 3;
    pri_s[tid] =
        rel_pri[(h * NN1 + u_s) * NE1 + e] * 0.17677669529663687f;
  }

  // ---------------- Phase 1: Qe[e][j] = Wq[e][j][:] . q ----------------
  for (int idx = tid; idx < NE1 * 128; idx += 256) {
    int e = idx >> 7, j = idx & 127;
    const float4* wr = (const float4*)(Wq + (size_t)(e * 128 + j) * 128);
    const float4* qv = (const float4*)q_s;
    float acc = 0.f;
#pragma unroll 4
    for (int c = 0; c < 32; ++c) {
      float4 w = wr[c], qq = qv[c];
      acc += w.x * qq.x + w.y * qq.y + w.z * qq.z + w.w * qq.w;
    }
    Qe_s[e][j] = acc;
  }
  __syncthreads();

  // ---- Phase 2: qM[e,h,d] = pri*rsdk * sum_i Qe[e][h*32+i]*Wk[e][h*32+i][d]
  for (int idx = tid; idx < 16 * 128; idx += 256) {
    int eh = idx >> 7, d = idx & 127;
    int e = eh >> 2, h = eh & 3;
    const float* wkb = Wk + ((size_t)(e * 128 + h * 32)) * 128 + d;
    float acc = 0.f;
#pragma unroll 4
    for (int i = 0; i < 32; ++i) acc += Qe_s[e][h * 32 + i] * wkb[i * 128];
    ehbuf[eh][d] = acc * pri_s[eh];
  }
  __syncthreads();

  // ---------------- Phase 3: logits, thread n handles 4 heads ----------------
  if (tid < N_) {
    const int n = tid;
    const float4* kr = (const float4*)(k + ((size_t)b * N_ + n) * D_);
    const int eh0 = et_s[n] * 4;
    const float4* m0 = (const float4*)&ehbuf[eh0 + 0][0];
    const float4* m1 = (const float4*)&ehbuf[eh0 + 1][0];
    const float4* m2 = (const float4*)&ehbuf[eh0 + 2][0];
    const float4* m3 = (const float4*)&ehbuf[eh0 + 3][0];
    float a0 = 0.f, a1 = 0.f, a2 = 0.f, a3 = 0.f;
#pragma unroll 2
    for (int c = 0; c < 32; ++c) {
      float4 kk = kr[c];
      float4 x0 = m0[c];
      a0 += kk.x * x0.x + kk.y * x0.y + kk.z * x0.z + kk.w * x0.w;
      float4 x1 = m1[c];
      a1 += kk.x * x1.x + kk.y * x1.y + kk.z * x1.z + kk.w * x1.w;
      float4 x2 = m2[c];
      a2 += kk.x * x2.x + kk.y * x2.y + kk.z * x2.z + kk.w * x2.w;
      float4 x3 = m3[c];
      a3 += kk.x * x3.x + kk.y * x3.y + kk.z * x3.z + kk.w * x3.w;
    }
    int m;
    if (flag[0])
      m = ((const unsigned char*)maskp)[(size_t)b * N_ + n];
    else
      m = ((const int*)maskp)[(size_t)b * N_ + n];
    if (m) { a0 = a1 = a2 = a3 = -1e10f; }
    p_s[0][n] = a0;
    p_s[1][n] = a1;
    p_s[2][n] = a2;
    p_s[3][n] = a3;
  }
  __syncthreads();

  // ---------------- Phase 4: softmax (one wave per head) + attn write ----------------
  {
    const int w = tid >> 6, l = tid & 63;
    float mx = -1e30f;
    for (int n = l; n < N_; n += 64) mx = fmaxf(mx, p_s[w][n]);
#pragma unroll
    for (int o = 32; o; o >>= 1) mx = fmaxf(mx, __shfl_xor(mx, o));
    float sum = 0.f;
    for (int n = l; n < N_; n += 64) {
      float e = __expf(p_s[w][n] - mx);
      p_s[w][n] = e;
      sum += e;
    }
#pragma unroll
    for (int o = 32; o; o >>= 1) sum += __shfl_xor(sum, o);
    float inv = 1.f / sum;
    for (int n = l; n < N_; n += 64) {
      float pp = p_s[w][n] * inv;
      p_s[w][n] = pp;
      attn_out[((size_t)w * B_ + b) * N_ + n] = pp;
    }
  }
  __syncthreads();

  // ---------------- Phase 5: PV accumulate s[h][e][d], v read direct ----------------
  {
    const int h = tid >> 6, l = tid & 63;
    float a0[4] = {0.f, 0.f, 0.f, 0.f}, a1[4] = {0.f, 0.f, 0.f, 0.f};
    const float* vb = v + (size_t)b * N_ * D_;
#pragma unroll 2
    for (int n = 0; n < N_; ++n) {
      float pv = p_s[h][n];
      int en = et_s[n];
      float v0 = vb[n * D_ + l], v1 = vb[n * D_ + 64 + l];
#pragma unroll
      for (int e = 0; e < 4; ++e) {
        float sel = (en == e) ? pv : 0.f;
        a0[e] = fmaf(sel, v0, a0[e]);
        a1[e] = fmaf(sel, v1, a1[e]);
      }
    }
#pragma unroll
    for (int e = 0; e < 4; ++e) {
      ehbuf[e * 4 + h][l] = a0[e];
      ehbuf[e * 4 + h][64 + l] = a1[e];
    }
  }
  __syncthreads();

  // ---------------- Phase 6: Wv contract, e split across thread halves ----------------
  {
    const int row = tid & 127, halfE = tid >> 7;
    const int hh = row >> 5;
    float acc = 0.f;
#pragma unroll
    for (int ee = 0; ee < 2; ++ee) {
      int e = halfE * 2 + ee;
      const float4* wr = (const float4*)(Wv + ((size_t)e * 128 + row) * 128);
      const float4* ss = (const float4*)&ehbuf[e * 4 + hh][0];
#pragma unroll 4
      for (int c = 0; c < 32; ++c) {
        float4 w = wr[c], sv = ss[c];
        acc += w.x * sv.x + w.y * sv.y + w.z * sv.z + w.w * sv.w;
      }
    }
    part_s[tid] = acc;
  }
  __syncthreads();

  // ---------------- Phase 7: FC (r-range split) + residual + LN ----------------
  {
    const int j = tid & 127, halfR = tid >> 7;
    const float* wf = W_fc + ((size_t)u_s * 128 + halfR * 64) * 128 + j;
    float acc = 0.f;
#pragma unroll 4
    for (int r = 0; r < 64; ++r) {
      float o = part_s[halfR * 64 + r] + part_s[128 + halfR * 64 + r];
      acc = fmaf(o, wf[r * 128], acc);
    }
    ((float*)p_s)[tid] = acc;
  }
  __syncthreads();

  float x = 0.f;
  if (tid < 128) {
    x = ((float*)p_s)[tid] + ((float*)p_s)[128 + tid] + b_fc[u_s * 128 + tid] +
        q_s[tid];
  }
  float s1 = (tid < 128) ? x : 0.f, s2 = (tid < 128) ? x * x : 0.f;
#pragma unroll
  for (int o = 32; o; o >>= 1) {
    s1 += __shfl_xor(s1, o);
    s2 += __shfl_xor(s2, o);
  }
  if (tid < 128 && (tid & 63) == 0) {
    red_s[tid >> 6] = s1;
    red_s[4 + (tid >> 6)] = s2;
  }
  __syncthreads();
  if (tid < 128) {
    float t1 = red_s[0] + red_s[1], t2 = red_s[4] + red_s[5];
    float mu = t1 * (1.f / 128.f);
    float var = t2 * (1.f / 128.f) - mu * mu;
    float yv = (x - mu) * rsqrtf(var + 1e-5f) * ln_gamma[tid] + ln_beta[tid];
    y_out[(size_t)b * 128 + tid] = yv;
  }
}

extern "C" void kernel_launch(void* const* d_in, const int* in_sizes, int n_in,
                              void* d_out, int out_size, void* d_ws,
                              size_t ws_size, hipStream_t stream) {
  const float* q = (const float*)d_in[0];
  const float* k = (const float*)d_in[1];
  const float* v = (const float*)d_in[2];
  const float* Wq = (const float*)d_in[3];
  const float* Wk = (const float*)d_in[4];
  const float* Wv = (const float*)d_in[5];
  const float* rp = (const float*)d_in[6];
  const float* Wf = (const float*)d_in[7];
  const float* bf = (const float*)d_in[8];
  const float* g = (const float*)d_in[9];
  const float* be = (const float*)d_in[10];
  const int* et = (const int*)d_in[11];
  const int* ut = (const int*)d_in[12];
  const void* mask = d_in[13];

  float* y = (float*)d_out;
  float* attn = y + (size_t)B_ * D_;
  unsigned int* flag = (unsigned int*)d_ws;

  hipMemsetAsync(d_ws, 0, 4, stream);
  detect_mask_kernel<<<64, 256, 0, stream>>>((const unsigned int*)mask,
                                             B_ * N_ / 4, flag);
  fused_mha_kernel<<<B_, 256, 0, stream>>>(q, k, v, Wq, Wk, Wv, rp, Wf, bf, g,
                                           be, et, ut, mask, flag, y, attn);
}

// Round 4
// 178.234 us; speedup vs baseline: 2.6539x; 1.4949x over previous
//
#include <hip/hip_runtime.h>

#define B_ 2048
#define N_ 200
#define D_ 128
#define NE1 4   // NE+1
#define NN1 3   // NN+1

// ---------------------------------------------------------------------------
// Mask storage detection (bool-bytes vs int32). Flag -> ws[0].
// ---------------------------------------------------------------------------
__global__ void detect_mask_kernel(const unsigned int* __restrict__ mw,
                                   int nwords, unsigned int* __restrict__ flag) {
  __shared__ int sbad;
  if (threadIdx.x == 0) sbad = 0;
  __syncthreads();
  int bad = 0;
  for (int i = blockIdx.x * blockDim.x + threadIdx.x; i < nwords;
       i += gridDim.x * blockDim.x)
    if (mw[i] > 1u) bad = 1;
  if (bad) sbad = 1;
  __syncthreads();
  if (threadIdx.x == 0 && sbad) atomicOr(flag, 1u);
}

// ---------------------------------------------------------------------------
// Fused kernel: one block per batch element b. ~16.5 KB LDS, VGPR<=64.
// All global reads coalesced (4-lane groups for row-dots) + batched loads.
// ---------------------------------------------------------------------------
__global__ __launch_bounds__(256, 8) void fused_mha_kernel(
    const float* __restrict__ q, const float* __restrict__ k,
    const float* __restrict__ v, const float* __restrict__ Wq,
    const float* __restrict__ Wk, const float* __restrict__ Wv,
    const float* __restrict__ rel_pri, const float* __restrict__ W_fc,
    const float* __restrict__ b_fc, const float* __restrict__ ln_gamma,
    const float* __restrict__ ln_beta, const int* __restrict__ etype,
    const int* __restrict__ utype, const void* __restrict__ maskp,
    const unsigned int* __restrict__ flag, float* __restrict__ y_out,
    float* __restrict__ attn_out) {
  const int b = blockIdx.x;
  const int tid = threadIdx.x;
  const int g = tid & 3, grp = tid >> 2;  // 4-lane groups, 64 groups

  __shared__ float q_s[128];
  __shared__ float Qe_s[4][132];
  __shared__ float ehbuf[16][132];  // qM (scaled); later s[h][e][:]
  __shared__ float p_s[4][200];     // logits -> probs; later FC partials
  __shared__ float msel[200];
  __shared__ int et_s[200];
  __shared__ float pri_s[16];  // [e*4+h], includes 1/sqrt(dk)
  __shared__ float part_s[128];
  __shared__ float red_s[8];
  __shared__ int u_s;

  // ---------------- Phase 0: per-b metadata ----------------
  if (tid == 0) u_s = utype[b];
  if (tid < 128) q_s[tid] = q[(size_t)b * D_ + tid];
  const unsigned int isBool = flag[0];
  for (int i = tid; i < N_; i += 256) {
    et_s[i] = etype[(size_t)b * N_ + i];
    int m;
    if (isBool)
      m = ((const unsigned char*)maskp)[(size_t)b * N_ + i];
    else
      m = ((const int*)maskp)[(size_t)b * N_ + i];
    msel[i] = m ? 1.f : 0.f;
  }
  __syncthreads();
  if (tid < 16) {
    int e = tid >> 2, h = tid & 3;
    pri_s[tid] = rel_pri[(h * NN1 + u_s) * NE1 + e] * 0.17677669529663687f;
  }

  // ------- Phase 1: Qe[e][j] = Wq[e][j][:].q  (4 lanes per output row) -------
  {
    const float4* qv = (const float4*)q_s;
#pragma unroll
    for (int pass = 0; pass < 8; ++pass) {
      int idx = pass * 64 + grp;  // 0..511
      int e = idx >> 7, j = idx & 127;
      const float4* wr = (const float4*)(Wq + (size_t)(e * 128 + j) * 128);
      float acc = 0.f;
#pragma unroll
      for (int half = 0; half < 2; ++half) {
        float4 wb[4];
#pragma unroll
        for (int t = 0; t < 4; ++t) wb[t] = wr[g + 4 * (half * 4 + t)];
#pragma unroll
        for (int t = 0; t < 4; ++t) {
          float4 qq = qv[g + 4 * (half * 4 + t)];
          acc += wb[t].x * qq.x + wb[t].y * qq.y + wb[t].z * qq.z +
                 wb[t].w * qq.w;
        }
      }
      acc += __shfl_xor(acc, 1);
      acc += __shfl_xor(acc, 2);
      if (g == 0) Qe_s[e][j] = acc;
    }
  }
  __syncthreads();

  // ---- Phase 2: qM[e,h,d] = pri * sum_i Qe[e][h*32+i]*Wk[e][h*32+i][d] ----
  // (threads d consecutive -> coalesced; weights column-walk)
  for (int idx = tid; idx < 16 * 128; idx += 256) {
    int eh = idx >> 7, d = idx & 127;
    int e = eh >> 2, h = eh & 3;
    const float* wkb = Wk + ((size_t)(e * 128 + h * 32)) * 128 + d;
    float acc = 0.f;
#pragma unroll
    for (int i4 = 0; i4 < 8; ++i4) {
      float w0 = wkb[(i4 * 4 + 0) * 128], w1 = wkb[(i4 * 4 + 1) * 128];
      float w2 = wkb[(i4 * 4 + 2) * 128], w3 = wkb[(i4 * 4 + 3) * 128];
      float4 qe = ((const float4*)&Qe_s[e][0])[h * 8 + i4];
      acc = fmaf(qe.x, w0, acc);
      acc = fmaf(qe.y, w1, acc);
      acc = fmaf(qe.z, w2, acc);
      acc = fmaf(qe.w, w3, acc);
    }
    ehbuf[eh][d] = acc * pri_s[eh];
  }
  __syncthreads();

  // ------- Phase 3: logits (4 lanes per n, all 4 heads per group) -------
  {
#pragma unroll
    for (int pass = 0; pass < 4; ++pass) {
      int n = pass * 64 + grp;
      if (n < N_) {
        const float4* kr = (const float4*)(k + ((size_t)b * N_ + n) * D_);
        const int eh0 = et_s[n] * 4;
        const float4* m0 = (const float4*)&ehbuf[eh0 + 0][0];
        const float4* m1 = (const float4*)&ehbuf[eh0 + 1][0];
        const float4* m2 = (const float4*)&ehbuf[eh0 + 2][0];
        const float4* m3 = (const float4*)&ehbuf[eh0 + 3][0];
        float a0 = 0.f, a1 = 0.f, a2 = 0.f, a3 = 0.f;
#pragma unroll
        for (int half = 0; half < 2; ++half) {
          float4 kb[4];
#pragma unroll
          for (int t = 0; t < 4; ++t) kb[t] = kr[g + 4 * (half * 4 + t)];
#pragma unroll
          for (int t = 0; t < 4; ++t) {
            int c = g + 4 * (half * 4 + t);
            float4 x0 = m0[c];
            a0 += kb[t].x * x0.x + kb[t].y * x0.y + kb[t].z * x0.z +
                  kb[t].w * x0.w;
            float4 x1 = m1[c];
            a1 += kb[t].x * x1.x + kb[t].y * x1.y + kb[t].z * x1.z +
                  kb[t].w * x1.w;
            float4 x2 = m2[c];
            a2 += kb[t].x * x2.x + kb[t].y * x2.y + kb[t].z * x2.z +
                  kb[t].w * x2.w;
            float4 x3 = m3[c];
            a3 += kb[t].x * x3.x + kb[t].y * x3.y + kb[t].z * x3.z +
                  kb[t].w * x3.w;
          }
        }
        a0 += __shfl_xor(a0, 1);
        a0 += __shfl_xor(a0, 2);
        a1 += __shfl_xor(a1, 1);
        a1 += __shfl_xor(a1, 2);
        a2 += __shfl_xor(a2, 1);
        a2 += __shfl_xor(a2, 2);
        a3 += __shfl_xor(a3, 1);
        a3 += __shfl_xor(a3, 2);
        if (g == 0) {
          bool m = msel[n] > 0.5f;
          p_s[0][n] = m ? -1e10f : a0;
          p_s[1][n] = m ? -1e10f : a1;
          p_s[2][n] = m ? -1e10f : a2;
          p_s[3][n] = m ? -1e10f : a3;
        }
      }
    }
  }
  __syncthreads();

  // ---------------- Phase 4: softmax (one wave per head) + attn write ----------------
  {
    const int w = tid >> 6, l = tid & 63;
    float mx = -1e30f;
    for (int n = l; n < N_; n += 64) mx = fmaxf(mx, p_s[w][n]);
#pragma unroll
    for (int o = 32; o; o >>= 1) mx = fmaxf(mx, __shfl_xor(mx, o));
    float sum = 0.f;
    for (int n = l; n < N_; n += 64) {
      float e = __expf(p_s[w][n] - mx);
      p_s[w][n] = e;
      sum += e;
    }
#pragma unroll
    for (int o = 32; o; o >>= 1) sum += __shfl_xor(sum, o);
    float inv = 1.f / sum;
    for (int n = l; n < N_; n += 64) {
      float pp = p_s[w][n] * inv;
      p_s[w][n] = pp;
      attn_out[((size_t)w * B_ + b) * N_ + n] = pp;
    }
  }
  __syncthreads();

  // ------- Phase 5: PV accumulate s[h][e][d]; batched v loads (8 in flight) -------
  {
    const int h = tid >> 6, l = tid & 63;
    float a0[4] = {0.f, 0.f, 0.f, 0.f}, a1[4] = {0.f, 0.f, 0.f, 0.f};
    const float* vb = v + (size_t)b * N_ * D_;
    for (int n = 0; n < N_; n += 4) {
      float v0[4], v1[4], pv[4];
      int en[4];
#pragma unroll
      for (int u = 0; u < 4; ++u) {
        v0[u] = vb[(n + u) * D_ + l];
        v1[u] = vb[(n + u) * D_ + 64 + l];
      }
#pragma unroll
      for (int u = 0; u < 4; ++u) {
        pv[u] = p_s[h][n + u];
        en[u] = et_s[n + u];
      }
#pragma unroll
      for (int u = 0; u < 4; ++u) {
#pragma unroll
        for (int e = 0; e < 4; ++e) {
          float sel = (en[u] == e) ? pv[u] : 0.f;
          a0[e] = fmaf(sel, v0[u], a0[e]);
          a1[e] = fmaf(sel, v1[u], a1[e]);
        }
      }
    }
#pragma unroll
    for (int e = 0; e < 4; ++e) {
      ehbuf[e * 4 + h][l] = a0[e];
      ehbuf[e * 4 + h][64 + l] = a1[e];
    }
  }
  __syncthreads();

  // ------- Phase 6: out[row] = sum_e Wv[e][row][:].s[h(row)][e][:] -------
  // 4 lanes per row; 2 passes over 128 rows.
  {
#pragma unroll
    for (int pass = 0; pass < 2; ++pass) {
      int row = pass * 64 + grp;
      int hh = row >> 5;
      float acc = 0.f;
#pragma unroll
      for (int e = 0; e < 4; ++e) {
        const float4* wr =
            (const float4*)(Wv + ((size_t)e * 128 + row) * 128);
        const float4* ss = (const float4*)&ehbuf[e * 4 + hh][0];
#pragma unroll
        for (int half = 0; half < 2; ++half) {
          float4 wb[4];
#pragma unroll
          for (int t = 0; t < 4; ++t) wb[t] = wr[g + 4 * (half * 4 + t)];
#pragma unroll
          for (int t = 0; t < 4; ++t) {
            float4 sv = ss[g + 4 * (half * 4 + t)];
            acc += wb[t].x * sv.x + wb[t].y * sv.y + wb[t].z * sv.z +
                   wb[t].w * sv.w;
          }
        }
      }
      acc += __shfl_xor(acc, 1);
      acc += __shfl_xor(acc, 2);
      if (g == 0) part_s[row] = acc;
    }
  }
  __syncthreads();

  // ---------------- Phase 7: FC (r-split) + residual + LN ----------------
  {
    const int j = tid & 127, halfR = tid >> 7;
    const float* wf = W_fc + ((size_t)u_s * 128 + halfR * 64) * 128 + j;
    float acc = 0.f;
    for (int r0 = 0; r0 < 64; r0 += 8) {
      float wv[8], ov[8];
#pragma unroll
      for (int u = 0; u < 8; ++u) wv[u] = wf[(r0 + u) * 128];
#pragma unroll
      for (int u = 0; u < 8; ++u) ov[u] = part_s[halfR * 64 + r0 + u];
#pragma unroll
      for (int u = 0; u < 8; ++u) acc = fmaf(ov[u], wv[u], acc);
    }
    ((float*)p_s)[tid] = acc;
  }
  __syncthreads();

  float x = 0.f;
  if (tid < 128) {
    x = ((float*)p_s)[tid] + ((float*)p_s)[128 + tid] + b_fc[u_s * 128 + tid] +
        q_s[tid];
  }
  float s1 = (tid < 128) ? x : 0.f, s2 = (tid < 128) ? x * x : 0.f;
#pragma unroll
  for (int o = 32; o; o >>= 1) {
    s1 += __shfl_xor(s1, o);
    s2 += __shfl_xor(s2, o);
  }
  if (tid < 128 && (tid & 63) == 0) {
    red_s[tid >> 6] = s1;
    red_s[4 + (tid >> 6)] = s2;
  }
  __syncthreads();
  if (tid < 128) {
    float t1 = red_s[0] + red_s[1], t2 = red_s[4] + red_s[5];
    float mu = t1 * (1.f / 128.f);
    float var = t2 * (1.f / 128.f) - mu * mu;
    float yv = (x - mu) * rsqrtf(var + 1e-5f) * ln_gamma[tid] + ln_beta[tid];
    y_out[(size_t)b * 128 + tid] = yv;
  }
}

extern "C" void kernel_launch(void* const* d_in, const int* in_sizes, int n_in,
                              void* d_out, int out_size, void* d_ws,
                              size_t ws_size, hipStream_t stream) {
  const float* q = (const float*)d_in[0];
  const float* k = (const float*)d_in[1];
  const float* v = (const float*)d_in[2];
  const float* Wq = (const float*)d_in[3];
  const float* Wk = (const float*)d_in[4];
  const float* Wv = (const float*)d_in[5];
  const float* rp = (const float*)d_in[6];
  const float* Wf = (const float*)d_in[7];
  const float* bf = (const float*)d_in[8];
  const float* g = (const float*)d_in[9];
  const float* be = (const float*)d_in[10];
  const int* et = (const int*)d_in[11];
  const int* ut = (const int*)d_in[12];
  const void* mask = d_in[13];

  float* y = (float*)d_out;
  float* attn = y + (size_t)B_ * D_;
  unsigned int* flag = (unsigned int*)d_ws;

  hipMemsetAsync(d_ws, 0, 4, stream);
  detect_mask_kernel<<<64, 256, 0, stream>>>((const unsigned int*)mask,
                                             B_ * N_ / 4, flag);
  fused_mha_kernel<<<B_, 256, 0, stream>>>(q, k, v, Wq, Wk, Wv, rp, Wf, bf, g,
                                           be, et, ut, mask, flag, y, attn);
}